// Round 1
// baseline (113.022 us; speedup 1.0000x reference)
//
#include <hip/hip_runtime.h>

// Problem constants (from reference setup_inputs)
#define BATCH   512
#define NELEC   100
#define NATOMS  20
#define SH      30
#define NORB    300
#define NBAS    600
#define NROWS   (BATCH * NELEC)   // 51200 (b,e) rows
#define RPT     8                 // rows per thread
#define NRG     (NROWS / RPT)     // 6400 row-groups
#define NTHREADS (NORB * NRG)     // 1,920,000

// One contracted-basis-function evaluation:
//   val = norm*coeff * r^n * exp(-alpha r^2) * x^kx y^ky z^kz
__device__ __forceinline__ float eval_basis(
    float px, float py, float pz,
    float ax, float ay, float az,
    float alpha, float n, float c,
    int kx, int ky, int kz)
{
    float dx = px - ax, dy = py - ay, dz = pz - az;
    float r2 = dx * dx + dy * dy + dz * dz;
    float r  = sqrtf(r2);
    // r^n for n in {0,1,2} (float-coded), branchless
    float R = (n < 0.5f) ? 1.0f : ((n < 1.5f) ? r : r2);
    float e = __expf(-alpha * r2);
    // x^k for k in {0,1,2}
    float yx = (kx == 0) ? 1.0f : dx;  yx = (kx == 2) ? yx * dx : yx;
    float yy = (ky == 0) ? 1.0f : dy;  yy = (ky == 2) ? yy * dy : yy;
    float yz = (kz == 0) ? 1.0f : dz;  yz = (kz == 2) ? yz * dz : yz;
    return c * R * e * (yx * yy * yz);
}

__global__ __launch_bounds__(256) void ao_kernel(
    const float* __restrict__ pos,          // (NROWS, 3)
    const float* __restrict__ atom_coords,  // (NATOMS, 3)
    const float* __restrict__ bas_exp,      // (NBAS)
    const float* __restrict__ bas_n,        // (NBAS)
    const float* __restrict__ norm_cst,     // (NBAS)
    const float* __restrict__ bas_coeffs,   // (NBAS)
    const int*   __restrict__ bas_kxyz,     // (NBAS, 3)
    float*       __restrict__ out)          // (NROWS, NORB)
{
    int tid = blockIdx.x * blockDim.x + threadIdx.x;
    if (tid >= NTHREADS) return;
    int o  = tid % NORB;       // orbital (fastest -> coalesced stores)
    int rg = tid / NORB;       // row-group

    // This orbital contracts basis 2o and 2o+1 (index_ctr = repeat(arange(NORB), 2))
    int s0 = 2 * o, s1 = s0 + 1;

    float a0 = bas_exp[s0],  a1 = bas_exp[s1];
    float n0 = bas_n[s0],    n1 = bas_n[s1];
    float c0 = norm_cst[s0] * bas_coeffs[s0];
    float c1 = norm_cst[s1] * bas_coeffs[s1];
    int kx0 = bas_kxyz[3 * s0 + 0], ky0 = bas_kxyz[3 * s0 + 1], kz0 = bas_kxyz[3 * s0 + 2];
    int kx1 = bas_kxyz[3 * s1 + 0], ky1 = bas_kxyz[3 * s1 + 1], kz1 = bas_kxyz[3 * s1 + 2];
    int at0 = s0 / SH, at1 = s1 / SH;
    float ax0 = atom_coords[3 * at0 + 0], ay0 = atom_coords[3 * at0 + 1], az0 = atom_coords[3 * at0 + 2];
    float ax1 = atom_coords[3 * at1 + 0], ay1 = atom_coords[3 * at1 + 1], az1 = atom_coords[3 * at1 + 2];

    int row0 = rg * RPT;
#pragma unroll
    for (int r = 0; r < RPT; ++r) {
        int row = row0 + r;
        float px = pos[row * 3 + 0];
        float py = pos[row * 3 + 1];
        float pz = pos[row * 3 + 2];
        float v0 = eval_basis(px, py, pz, ax0, ay0, az0, a0, n0, c0, kx0, ky0, kz0);
        float v1 = eval_basis(px, py, pz, ax1, ay1, az1, a1, n1, c1, kx1, ky1, kz1);
        out[row * NORB + o] = v0 + v1;
    }
}

extern "C" void kernel_launch(void* const* d_in, const int* in_sizes, int n_in,
                              void* d_out, int out_size, void* d_ws, size_t ws_size,
                              hipStream_t stream) {
    const float* pos         = (const float*)d_in[0];
    const float* atom_coords = (const float*)d_in[1];
    const float* bas_exp     = (const float*)d_in[2];
    const float* bas_n       = (const float*)d_in[3];
    const float* norm_cst    = (const float*)d_in[4];
    const float* bas_coeffs  = (const float*)d_in[5];
    const int*   bas_kxyz    = (const int*)d_in[6];
    // d_in[7] = index_ctr (repeat(arange(NORB), 2)) — mapping hardcoded as s -> s/2
    float* out = (float*)d_out;

    int blocks = (NTHREADS + 255) / 256;  // 7500
    ao_kernel<<<blocks, 256, 0, stream>>>(pos, atom_coords, bas_exp, bas_n,
                                          norm_cst, bas_coeffs, bas_kxyz, out);
}